// Round 2
// baseline (1025.403 us; speedup 1.0000x reference)
//
#include <hip/hip_runtime.h>

// ---------- types / helpers ----------
typedef __bf16 bf16x8 __attribute__((ext_vector_type(8)));
typedef unsigned short u16x8 __attribute__((ext_vector_type(8)));
typedef float f32x4 __attribute__((ext_vector_type(4)));

static __device__ __forceinline__ float b2f(unsigned short u) {
    return __uint_as_float(((unsigned)u) << 16);
}
static __device__ __forceinline__ unsigned short f2b(float f) {
    unsigned u = __float_as_uint(f);
    unsigned r = (u + 0x7FFF + ((u >> 16) & 1)) >> 16;  // RNE
    return (unsigned short)r;
}

// ---------- degree ----------
__global__ __launch_bounds__(256) void deg_kernel(const int* __restrict__ ei,
                                                  int* __restrict__ deg, int E) {
    int e = blockIdx.x * 256 + threadIdx.x;
    if (e < E) atomicAdd(&deg[ei[E + e]], 1);  // dst row
}

__global__ __launch_bounds__(256) void dinv_kernel(const int* __restrict__ deg,
                                                   float* __restrict__ dinv, int n) {
    int i = blockIdx.x * 256 + threadIdx.x;
    if (i < n) dinv[i] = rsqrtf((float)deg[i] + 1.0f);  // +1 self-loop
}

// ---------- hierarchical exclusive scan (1024 elems / block) ----------
__global__ __launch_bounds__(256) void scan1_kernel(const int* __restrict__ deg,
                                                    int* __restrict__ excl,
                                                    int* __restrict__ chunk_sum, int n) {
    __shared__ int s[256];
    int tid = threadIdx.x;
    int base = blockIdx.x * 1024 + tid * 4;
    int v[4], sum = 0;
#pragma unroll
    for (int j = 0; j < 4; ++j) {
        v[j] = (base + j < n) ? deg[base + j] : 0;
        sum += v[j];
    }
    s[tid] = sum;
    __syncthreads();
    for (int off = 1; off < 256; off <<= 1) {
        int t = (tid >= off) ? s[tid - off] : 0;
        __syncthreads();
        s[tid] += t;
        __syncthreads();
    }
    int run = s[tid] - sum;  // exclusive prefix of this thread within block
#pragma unroll
    for (int j = 0; j < 4; ++j) {
        if (base + j < n) excl[base + j] = run;
        run += v[j];
    }
    if (tid == 255) chunk_sum[blockIdx.x] = s[255];
}

__global__ __launch_bounds__(128) void scan2_kernel(const int* __restrict__ chunk_sum,
                                                    int* __restrict__ chunk_off, int nc) {
    __shared__ int s[128];
    int tid = threadIdx.x;
    int v = (tid < nc) ? chunk_sum[tid] : 0;
    s[tid] = v;
    __syncthreads();
    for (int off = 1; off < 128; off <<= 1) {
        int t = (tid >= off) ? s[tid - off] : 0;
        __syncthreads();
        s[tid] += t;
        __syncthreads();
    }
    if (tid < nc) chunk_off[tid] = s[tid] - v;  // exclusive
}

__global__ __launch_bounds__(256) void scan3_kernel(const int* __restrict__ excl,
                                                    const int* __restrict__ chunk_off,
                                                    int* __restrict__ row_ptr,
                                                    int* __restrict__ fill_pos, int n, int E) {
    int i = blockIdx.x * 256 + threadIdx.x;
    if (i < n) {
        int r = excl[i] + chunk_off[i >> 10];
        row_ptr[i] = r;
        fill_pos[i] = r;
    }
    if (i == 0) row_ptr[n] = E;
}

// ---------- CSR fill ----------
__global__ __launch_bounds__(256) void fill_kernel(const int* __restrict__ ei,
                                                   int* __restrict__ fill_pos,
                                                   int* __restrict__ csr_src, int E) {
    int e = blockIdx.x * 256 + threadIdx.x;
    if (e >= E) return;
    int dst = ei[E + e];
    int p = atomicAdd(&fill_pos[dst], 1);
    csr_src[p] = ei[e];
}

// ---------- weight split+transpose: Whi/Wlo[n*K + k] = split(W[k*Ncol + n]) ----------
__global__ __launch_bounds__(256) void wsplit_kernel(const float* __restrict__ W,
                                                     unsigned short* __restrict__ Whi,
                                                     unsigned short* __restrict__ Wlo,
                                                     int K, int Ncol) {
    int idx = blockIdx.x * 256 + threadIdx.x;
    if (idx >= K * Ncol) return;
    int k = idx / Ncol, n = idx - k * Ncol;
    float a = W[idx];
    unsigned short hb = f2b(a);
    Whi[n * K + k] = hb;
    Wlo[n * K + k] = f2b(a - b2f(hb));
}

// ---------- split 8 f32 -> hi/lo bf16x8 ----------
union BU {
    u16x8 u;
    bf16x8 b;
};
static __device__ __forceinline__ void split8(const float4 a01, const float4 a23,
                                              bf16x8& hi, bf16x8& lo) {
    float a[8] = {a01.x, a01.y, a01.z, a01.w, a23.x, a23.y, a23.z, a23.w};
    BU h, l;
#pragma unroll
    for (int j = 0; j < 8; ++j) {
        unsigned short hb = f2b(a[j]);
        h.u[j] = hb;
        l.u[j] = f2b(a[j] - b2f(hb));
    }
    hi = h.b;
    lo = l.b;
}

// ---------- MFMA GEMM (split bf16): C[nrows, NT*16] = A[nrows,128] @ W ----------
// 4 waves/block, 16 rows/wave. K = 128. A fp32 in global, W pre-split/transposed.
// EPI=false: C = (A@W) * dinv[row]   (f32 store)
// EPI=true : C = relu(A@W + bias)    (f32 store)
template <int NT, bool EPI>
__global__ __launch_bounds__(256) void gemm_kernel(const float* __restrict__ A,
                                                   const unsigned short* __restrict__ Whi,
                                                   const unsigned short* __restrict__ Wlo,
                                                   const float* __restrict__ bias,
                                                   const float* __restrict__ dinv,
                                                   float* __restrict__ C, int nrows) {
    const int tid = threadIdx.x;
    const int wave = tid >> 6;
    const int lane = tid & 63;
    const int m16 = lane & 15;
    const int quad = lane >> 4;
    const int row_base = blockIdx.x * 64 + wave * 16;
    int arow = row_base + m16;
    if (arow >= nrows) arow = nrows - 1;  // clamp; stores are guarded

    f32x4 acc[NT] = {};
    const float* Arow = A + (size_t)arow * 128 + quad * 8;
#pragma unroll
    for (int kb = 0; kb < 4; ++kb) {
        float4 a01 = *reinterpret_cast<const float4*>(Arow + kb * 32);
        float4 a23 = *reinterpret_cast<const float4*>(Arow + kb * 32 + 4);
        bf16x8 ahi, alo;
        split8(a01, a23, ahi, alo);
#pragma unroll
        for (int t = 0; t < NT; ++t) {
            size_t woff = (size_t)(t * 16 + m16) * 128 + quad * 8 + kb * 32;
            BU bh, bl;
            bh.u = *reinterpret_cast<const u16x8*>(Whi + woff);
            bl.u = *reinterpret_cast<const u16x8*>(Wlo + woff);
            acc[t] = __builtin_amdgcn_mfma_f32_16x16x32_bf16(ahi, bh.b, acc[t], 0, 0, 0);
            acc[t] = __builtin_amdgcn_mfma_f32_16x16x32_bf16(ahi, bl.b, acc[t], 0, 0, 0);
            acc[t] = __builtin_amdgcn_mfma_f32_16x16x32_bf16(alo, bh.b, acc[t], 0, 0, 0);
        }
    }
    const int ncols = NT * 16;
#pragma unroll
    for (int t = 0; t < NT; ++t) {
#pragma unroll
        for (int r = 0; r < 4; ++r) {
            int row = row_base + quad * 4 + r;
            if (row < nrows) {
                float v = acc[t][r];
                if (EPI) {
                    v = fmaxf(v + bias[t * 16 + m16], 0.0f);
                } else {
                    v *= dinv[row];
                }
                C[(size_t)row * ncols + t * 16 + m16] = v;
            }
        }
    }
}

// ---------- pull aggregation: out = relu(dinv[i]*(sum_in hs[src] + hs[i]) + b) ----------
// 32 lanes per node, 4 feats per lane.
__global__ __launch_bounds__(256) void pull_kernel(const float* __restrict__ hs,
                                                   const int* __restrict__ row_ptr,
                                                   const int* __restrict__ csr_src,
                                                   const float* __restrict__ dinv,
                                                   const float* __restrict__ bias,
                                                   float* __restrict__ out, int n) {
    int t = blockIdx.x * 256 + threadIdx.x;
    int node = t >> 5;
    if (node >= n) return;
    int f = (t & 31) * 4;
    float4 acc = *reinterpret_cast<const float4*>(hs + (size_t)node * 128 + f);  // self loop
    int s0 = row_ptr[node], s1 = row_ptr[node + 1];
    for (int e = s0; e < s1; ++e) {
        int src = csr_src[e];
        float4 hv = *reinterpret_cast<const float4*>(hs + (size_t)src * 128 + f);
        acc.x += hv.x;
        acc.y += hv.y;
        acc.z += hv.z;
        acc.w += hv.w;
    }
    float d = dinv[node];
    float4 o;
    o.x = fmaxf(acc.x * d + bias[f + 0], 0.f);
    o.y = fmaxf(acc.y * d + bias[f + 1], 0.f);
    o.z = fmaxf(acc.z * d + bias[f + 2], 0.f);
    o.w = fmaxf(acc.w * d + bias[f + 3], 0.f);
    *reinterpret_cast<float4*>(out + (size_t)node * 128 + f) = o;
}

// ---------- final heads: one wave per node; out [N,3] f32 ----------
__global__ __launch_bounds__(256) void head_kernel(const float* __restrict__ ph,
                                                   const float* __restrict__ th,
                                                   const float* __restrict__ Wp2,
                                                   const float* __restrict__ bp2,
                                                   const float* __restrict__ Wt2,
                                                   const float* __restrict__ bt2,
                                                   float* __restrict__ out, int n) {
    int g = blockIdx.x * 256 + threadIdx.x;
    int node = g >> 6;
    int lane = threadIdx.x & 63;
    if (node >= n) return;
    float a0 = ph[(size_t)node * 128 + lane];
    float a1 = ph[(size_t)node * 128 + 64 + lane];
    float p0 = a0 * Wp2[lane * 2 + 0] + a1 * Wp2[(lane + 64) * 2 + 0];
    float p1 = a0 * Wp2[lane * 2 + 1] + a1 * Wp2[(lane + 64) * 2 + 1];
    float tt = th[(size_t)node * 64 + lane] * Wt2[lane];
#pragma unroll
    for (int off = 32; off > 0; off >>= 1) {
        p0 += __shfl_down(p0, off);
        p1 += __shfl_down(p1, off);
        tt += __shfl_down(tt, off);
    }
    if (lane == 0) {
        out[(size_t)node * 3 + 0] = p0 + bp2[0];
        out[(size_t)node * 3 + 1] = p1 + bp2[1];
        out[(size_t)node * 3 + 2] = tt + bt2[0];
    }
}

// ---------- launcher ----------
extern "C" void kernel_launch(void* const* d_in, const int* in_sizes, int n_in,
                              void* d_out, int out_size, void* d_ws, size_t ws_size,
                              hipStream_t stream) {
    const int N = in_sizes[0] / 128;
    const int E = in_sizes[1] / 2;

    const float* x   = (const float*)d_in[0];
    const int* ei    = (const int*)d_in[1];
    const float* W1  = (const float*)d_in[2];
    const float* b1  = (const float*)d_in[3];
    const float* W2  = (const float*)d_in[4];
    const float* b2  = (const float*)d_in[5];
    const float* W3  = (const float*)d_in[6];
    const float* b3  = (const float*)d_in[7];
    const float* Wp1 = (const float*)d_in[8];
    const float* bp1 = (const float*)d_in[9];
    const float* Wp2 = (const float*)d_in[10];
    const float* bp2 = (const float*)d_in[11];
    const float* Wt1 = (const float*)d_in[12];
    const float* bt1 = (const float*)d_in[13];
    const float* Wt2 = (const float*)d_in[14];
    const float* bt2 = (const float*)d_in[15];
    float* out = (float*)d_out;

    char* ws = (char*)d_ws;
    size_t off = 0;
    auto alloc = [&](size_t bytes) {
        void* p = ws + off;
        off += (bytes + 255) & ~(size_t)255;
        return p;
    };
    int* deg        = (int*)alloc((size_t)N * 4);
    float* dinv     = (float*)alloc((size_t)N * 4);
    int* excl       = (int*)alloc((size_t)N * 4);
    int* row_ptr    = (int*)alloc((size_t)(N + 1) * 4);
    int* fill_pos   = (int*)alloc((size_t)N * 4);
    int* chunk_sum  = (int*)alloc(128 * 4);
    int* chunk_off  = (int*)alloc(128 * 4);
    int* csr_src    = (int*)alloc((size_t)E * 4);
    unsigned short* W1hi  = (unsigned short*)alloc(16384 * 2);
    unsigned short* W1lo  = (unsigned short*)alloc(16384 * 2);
    unsigned short* W2hi  = (unsigned short*)alloc(16384 * 2);
    unsigned short* W2lo  = (unsigned short*)alloc(16384 * 2);
    unsigned short* W3hi  = (unsigned short*)alloc(16384 * 2);
    unsigned short* W3lo  = (unsigned short*)alloc(16384 * 2);
    unsigned short* Wp1hi = (unsigned short*)alloc(16384 * 2);
    unsigned short* Wp1lo = (unsigned short*)alloc(16384 * 2);
    unsigned short* Wt1hi = (unsigned short*)alloc(8192 * 2);
    unsigned short* Wt1lo = (unsigned short*)alloc(8192 * 2);
    float* bufA = (float*)alloc((size_t)N * 128 * 4);
    float* bufB = (float*)alloc((size_t)N * 128 * 4);
    float* bufC = (float*)alloc((size_t)N * 64 * 4);

    // degree + norm
    hipMemsetAsync(deg, 0, (size_t)N * 4, stream);
    deg_kernel<<<(E + 255) / 256, 256, 0, stream>>>(ei, deg, E);
    dinv_kernel<<<(N + 255) / 256, 256, 0, stream>>>(deg, dinv, N);

    // CSR build
    const int nb1 = (N + 1023) / 1024;
    scan1_kernel<<<nb1, 256, 0, stream>>>(deg, excl, chunk_sum, N);
    scan2_kernel<<<1, 128, 0, stream>>>(chunk_sum, chunk_off, nb1);
    scan3_kernel<<<(N + 255) / 256, 256, 0, stream>>>(excl, chunk_off, row_ptr, fill_pos, N, E);
    fill_kernel<<<(E + 255) / 256, 256, 0, stream>>>(ei, fill_pos, csr_src, E);

    // weight split+transpose
    wsplit_kernel<<<64, 256, 0, stream>>>(W1, W1hi, W1lo, 128, 128);
    wsplit_kernel<<<64, 256, 0, stream>>>(W2, W2hi, W2lo, 128, 128);
    wsplit_kernel<<<64, 256, 0, stream>>>(W3, W3hi, W3lo, 128, 128);
    wsplit_kernel<<<64, 256, 0, stream>>>(Wp1, Wp1hi, Wp1lo, 128, 128);
    wsplit_kernel<<<32, 256, 0, stream>>>(Wt1, Wt1hi, Wt1lo, 128, 64);

    const int gemm_blocks = (N + 63) / 64;
    const int pull_blocks = (N + 7) / 8;

    // layer 1: GEMM(x) -> bufA (hs), pull(bufA) -> bufB
    gemm_kernel<8, false><<<gemm_blocks, 256, 0, stream>>>(x, W1hi, W1lo, nullptr, dinv, bufA, N);
    pull_kernel<<<pull_blocks, 256, 0, stream>>>(bufA, row_ptr, csr_src, dinv, b1, bufB, N);
    // layer 2
    gemm_kernel<8, false><<<gemm_blocks, 256, 0, stream>>>(bufB, W2hi, W2lo, nullptr, dinv, bufA, N);
    pull_kernel<<<pull_blocks, 256, 0, stream>>>(bufA, row_ptr, csr_src, dinv, b2, bufB, N);
    // layer 3
    gemm_kernel<8, false><<<gemm_blocks, 256, 0, stream>>>(bufB, W3hi, W3lo, nullptr, dinv, bufA, N);
    pull_kernel<<<pull_blocks, 256, 0, stream>>>(bufA, row_ptr, csr_src, dinv, b3, bufB, N);

    // heads
    gemm_kernel<8, true><<<gemm_blocks, 256, 0, stream>>>(bufB, Wp1hi, Wp1lo, bp1, nullptr, bufA, N);
    gemm_kernel<4, true><<<gemm_blocks, 256, 0, stream>>>(bufB, Wt1hi, Wt1lo, bt1, nullptr, bufC, N);
    head_kernel<<<(N + 3) / 4, 256, 0, stream>>>(bufA, bufC, Wp2, bp2, Wt2, bt2, out, N);
}

// Round 3
// 860.439 us; speedup vs baseline: 1.1917x; 1.1917x over previous
//
#include <hip/hip_runtime.h>

// ---------- types / helpers ----------
typedef __bf16 bf16x8 __attribute__((ext_vector_type(8)));
typedef unsigned short u16x8 __attribute__((ext_vector_type(8)));
typedef float f32x4 __attribute__((ext_vector_type(4)));

union BU {
    u16x8 u;
    bf16x8 b;
};

static __device__ __forceinline__ float b2f(unsigned short u) {
    return __uint_as_float(((unsigned)u) << 16);
}
static __device__ __forceinline__ unsigned short f2b(float f) {
    unsigned u = __float_as_uint(f);
    unsigned r = (u + 0x7FFF + ((u >> 16) & 1)) >> 16;  // RNE
    return (unsigned short)r;
}

// ---------- degree ----------
__global__ __launch_bounds__(256) void deg_kernel(const int* __restrict__ ei,
                                                  int* __restrict__ deg, int E) {
    int e = blockIdx.x * 256 + threadIdx.x;
    if (e < E) atomicAdd(&deg[ei[E + e]], 1);  // dst row
}

__global__ __launch_bounds__(256) void dinv_kernel(const int* __restrict__ deg,
                                                   float* __restrict__ dinv, int n) {
    int i = blockIdx.x * 256 + threadIdx.x;
    if (i < n) dinv[i] = rsqrtf((float)deg[i] + 1.0f);  // +1 self-loop
}

// ---------- hierarchical exclusive scan (1024 elems / block) ----------
__global__ __launch_bounds__(256) void scan1_kernel(const int* __restrict__ deg,
                                                    int* __restrict__ excl,
                                                    int* __restrict__ chunk_sum, int n) {
    __shared__ int s[256];
    int tid = threadIdx.x;
    int base = blockIdx.x * 1024 + tid * 4;
    int v[4], sum = 0;
#pragma unroll
    for (int j = 0; j < 4; ++j) {
        v[j] = (base + j < n) ? deg[base + j] : 0;
        sum += v[j];
    }
    s[tid] = sum;
    __syncthreads();
    for (int off = 1; off < 256; off <<= 1) {
        int t = (tid >= off) ? s[tid - off] : 0;
        __syncthreads();
        s[tid] += t;
        __syncthreads();
    }
    int run = s[tid] - sum;
#pragma unroll
    for (int j = 0; j < 4; ++j) {
        if (base + j < n) excl[base + j] = run;
        run += v[j];
    }
    if (tid == 255) chunk_sum[blockIdx.x] = s[255];
}

__global__ __launch_bounds__(128) void scan2_kernel(const int* __restrict__ chunk_sum,
                                                    int* __restrict__ chunk_off, int nc) {
    __shared__ int s[128];
    int tid = threadIdx.x;
    int v = (tid < nc) ? chunk_sum[tid] : 0;
    s[tid] = v;
    __syncthreads();
    for (int off = 1; off < 128; off <<= 1) {
        int t = (tid >= off) ? s[tid - off] : 0;
        __syncthreads();
        s[tid] += t;
        __syncthreads();
    }
    if (tid < nc) chunk_off[tid] = s[tid] - v;
}

__global__ __launch_bounds__(256) void scan3_kernel(const int* __restrict__ excl,
                                                    const int* __restrict__ chunk_off,
                                                    int* __restrict__ row_ptr,
                                                    int* __restrict__ fill_pos, int n, int E) {
    int i = blockIdx.x * 256 + threadIdx.x;
    if (i < n) {
        int r = excl[i] + chunk_off[i >> 10];
        row_ptr[i] = r;
        fill_pos[i] = r;
    }
    if (i == 0) row_ptr[n] = E;
}

// ---------- CSR fill ----------
__global__ __launch_bounds__(256) void fill_kernel(const int* __restrict__ ei,
                                                   int* __restrict__ fill_pos,
                                                   int* __restrict__ csr_src, int E) {
    int e = blockIdx.x * 256 + threadIdx.x;
    if (e >= E) return;
    int dst = ei[E + e];
    int p = atomicAdd(&fill_pos[dst], 1);
    csr_src[p] = ei[e];
}

// ---------- weight split+transpose: Whi/Wlo[n*K + k] = split(W[k*Ncol + n]) ----------
__global__ __launch_bounds__(256) void wsplit_kernel(const float* __restrict__ W,
                                                     unsigned short* __restrict__ Whi,
                                                     unsigned short* __restrict__ Wlo,
                                                     int K, int Ncol) {
    int idx = blockIdx.x * 256 + threadIdx.x;
    if (idx >= K * Ncol) return;
    int k = idx / Ncol, n = idx - k * Ncol;
    float a = W[idx];
    unsigned short hb = f2b(a);
    Whi[n * K + k] = hb;
    Wlo[n * K + k] = f2b(a - b2f(hb));
}

// ---------- bias concat: bcat[0:128)=bp1, [128:192)=bt1 ----------
__global__ __launch_bounds__(256) void bcat_kernel(const float* __restrict__ bp1,
                                                   const float* __restrict__ bt1,
                                                   float* __restrict__ bcat) {
    int i = threadIdx.x;
    if (i < 128) bcat[i] = bp1[i];
    else if (i < 192) bcat[i] = bt1[i - 128];
}

// ---------- round f32 -> bf16 ----------
__global__ __launch_bounds__(256) void round_kernel(const float* __restrict__ x,
                                                    unsigned short* __restrict__ xb, int n4) {
    int i = blockIdx.x * 256 + threadIdx.x;
    if (i >= n4) return;
    float4 v = *reinterpret_cast<const float4*>(x + (size_t)i * 4);
    ushort4 o;
    o.x = f2b(v.x);
    o.y = f2b(v.y);
    o.z = f2b(v.z);
    o.w = f2b(v.w);
    *reinterpret_cast<ushort4*>(xb + (size_t)i * 4) = o;
}

// ---------- MFMA GEMM (bf16 A, split-bf16 W): C[nrows, NT*16] = A @ W ----------
// 4 waves/block, 16 rows/wave. K = 128. fp32 accum.
// EPI=false: C = (A@W) * dinv[row]   -> bf16
// EPI=true : C = relu(A@W + bias)    -> bf16
template <int NT, bool EPI>
__global__ __launch_bounds__(256) void gemm_kernel(const unsigned short* __restrict__ A,
                                                   const unsigned short* __restrict__ Whi,
                                                   const unsigned short* __restrict__ Wlo,
                                                   const float* __restrict__ bias,
                                                   const float* __restrict__ dinv,
                                                   unsigned short* __restrict__ C, int nrows) {
    const int tid = threadIdx.x;
    const int wave = tid >> 6;
    const int lane = tid & 63;
    const int m16 = lane & 15;
    const int quad = lane >> 4;
    const int row_base = blockIdx.x * 64 + wave * 16;
    int arow = row_base + m16;
    if (arow >= nrows) arow = nrows - 1;  // clamp; stores are guarded

    f32x4 acc[NT] = {};
    const unsigned short* Arow = A + (size_t)arow * 128 + quad * 8;
#pragma unroll
    for (int kb = 0; kb < 4; ++kb) {
        BU a;
        a.u = *reinterpret_cast<const u16x8*>(Arow + kb * 32);
#pragma unroll
        for (int t = 0; t < NT; ++t) {
            size_t woff = (size_t)(t * 16 + m16) * 128 + quad * 8 + kb * 32;
            BU bh, bl;
            bh.u = *reinterpret_cast<const u16x8*>(Whi + woff);
            bl.u = *reinterpret_cast<const u16x8*>(Wlo + woff);
            acc[t] = __builtin_amdgcn_mfma_f32_16x16x32_bf16(a.b, bh.b, acc[t], 0, 0, 0);
            acc[t] = __builtin_amdgcn_mfma_f32_16x16x32_bf16(a.b, bl.b, acc[t], 0, 0, 0);
        }
    }
    const int ncols = NT * 16;
#pragma unroll
    for (int t = 0; t < NT; ++t) {
#pragma unroll
        for (int r = 0; r < 4; ++r) {
            int row = row_base + quad * 4 + r;
            if (row < nrows) {
                float v = acc[t][r];
                if (EPI) {
                    v = fmaxf(v + bias[t * 16 + m16], 0.0f);
                } else {
                    v *= dinv[row];
                }
                C[(size_t)row * ncols + t * 16 + m16] = f2b(v);
            }
        }
    }
}

// ---------- pull aggregation: out = relu(dinv[i]*(sum_in hs[src] + hs[i]) + b) ----------
// 32 lanes per node, 4 feats per lane; bf16 in/out, fp32 accum; 2-unrolled gather.
__global__ __launch_bounds__(256) void pull_kernel(const unsigned short* __restrict__ hs,
                                                   const int* __restrict__ row_ptr,
                                                   const int* __restrict__ csr_src,
                                                   const float* __restrict__ dinv,
                                                   const float* __restrict__ bias,
                                                   unsigned short* __restrict__ out, int n) {
    int t = blockIdx.x * 256 + threadIdx.x;
    int node = t >> 5;
    if (node >= n) return;
    int f = (t & 31) * 4;
    ushort4 sv = *reinterpret_cast<const ushort4*>(hs + (size_t)node * 128 + f);
    float ax = b2f(sv.x), ay = b2f(sv.y), az = b2f(sv.z), aw = b2f(sv.w);  // self loop
    int s0 = row_ptr[node], s1 = row_ptr[node + 1];
    int e = s0;
    for (; e + 2 <= s1; e += 2) {
        int src0 = csr_src[e];
        int src1 = csr_src[e + 1];
        ushort4 h0 = *reinterpret_cast<const ushort4*>(hs + (size_t)src0 * 128 + f);
        ushort4 h1 = *reinterpret_cast<const ushort4*>(hs + (size_t)src1 * 128 + f);
        ax += b2f(h0.x) + b2f(h1.x);
        ay += b2f(h0.y) + b2f(h1.y);
        az += b2f(h0.z) + b2f(h1.z);
        aw += b2f(h0.w) + b2f(h1.w);
    }
    if (e < s1) {
        int src0 = csr_src[e];
        ushort4 h0 = *reinterpret_cast<const ushort4*>(hs + (size_t)src0 * 128 + f);
        ax += b2f(h0.x);
        ay += b2f(h0.y);
        az += b2f(h0.z);
        aw += b2f(h0.w);
    }
    float d = dinv[node];
    ushort4 o;
    o.x = f2b(fmaxf(ax * d + bias[f + 0], 0.f));
    o.y = f2b(fmaxf(ay * d + bias[f + 1], 0.f));
    o.z = f2b(fmaxf(az * d + bias[f + 2], 0.f));
    o.w = f2b(fmaxf(aw * d + bias[f + 3], 0.f));
    *reinterpret_cast<ushort4*>(out + (size_t)node * 128 + f) = o;
}

// ---------- final heads: one wave per node; hidden bf16 [N,192]; out [N,3] f32 ----------
__global__ __launch_bounds__(256) void head_kernel(const unsigned short* __restrict__ hh,
                                                   const float* __restrict__ Wp2,
                                                   const float* __restrict__ bp2,
                                                   const float* __restrict__ Wt2,
                                                   const float* __restrict__ bt2,
                                                   float* __restrict__ out, int n) {
    int g = blockIdx.x * 256 + threadIdx.x;
    int node = g >> 6;
    int lane = threadIdx.x & 63;
    if (node >= n) return;
    const unsigned short* row = hh + (size_t)node * 192;
    float a0 = b2f(row[lane]);
    float a1 = b2f(row[64 + lane]);
    float at = b2f(row[128 + lane]);
    float p0 = a0 * Wp2[lane * 2 + 0] + a1 * Wp2[(lane + 64) * 2 + 0];
    float p1 = a0 * Wp2[lane * 2 + 1] + a1 * Wp2[(lane + 64) * 2 + 1];
    float tt = at * Wt2[lane];
#pragma unroll
    for (int off = 32; off > 0; off >>= 1) {
        p0 += __shfl_down(p0, off);
        p1 += __shfl_down(p1, off);
        tt += __shfl_down(tt, off);
    }
    if (lane == 0) {
        out[(size_t)node * 3 + 0] = p0 + bp2[0];
        out[(size_t)node * 3 + 1] = p1 + bp2[1];
        out[(size_t)node * 3 + 2] = tt + bt2[0];
    }
}

// ---------- launcher ----------
extern "C" void kernel_launch(void* const* d_in, const int* in_sizes, int n_in,
                              void* d_out, int out_size, void* d_ws, size_t ws_size,
                              hipStream_t stream) {
    const int N = in_sizes[0] / 128;
    const int E = in_sizes[1] / 2;

    const float* x   = (const float*)d_in[0];
    const int* ei    = (const int*)d_in[1];
    const float* W1  = (const float*)d_in[2];
    const float* b1  = (const float*)d_in[3];
    const float* W2  = (const float*)d_in[4];
    const float* b2  = (const float*)d_in[5];
    const float* W3  = (const float*)d_in[6];
    const float* b3  = (const float*)d_in[7];
    const float* Wp1 = (const float*)d_in[8];
    const float* bp1 = (const float*)d_in[9];
    const float* Wp2 = (const float*)d_in[10];
    const float* bp2 = (const float*)d_in[11];
    const float* Wt1 = (const float*)d_in[12];
    const float* bt1 = (const float*)d_in[13];
    const float* Wt2 = (const float*)d_in[14];
    const float* bt2 = (const float*)d_in[15];
    float* out = (float*)d_out;

    char* ws = (char*)d_ws;
    size_t off = 0;
    auto alloc = [&](size_t bytes) {
        void* p = ws + off;
        off += (bytes + 255) & ~(size_t)255;
        return p;
    };
    int* deg        = (int*)alloc((size_t)N * 4);
    float* dinv     = (float*)alloc((size_t)N * 4);
    int* excl       = (int*)alloc((size_t)N * 4);
    int* row_ptr    = (int*)alloc((size_t)(N + 1) * 4);
    int* fill_pos   = (int*)alloc((size_t)N * 4);
    int* chunk_sum  = (int*)alloc(128 * 4);
    int* chunk_off  = (int*)alloc(128 * 4);
    int* csr_src    = (int*)alloc((size_t)E * 4);
    unsigned short* W1hi  = (unsigned short*)alloc(16384 * 2);
    unsigned short* W1lo  = (unsigned short*)alloc(16384 * 2);
    unsigned short* W2hi  = (unsigned short*)alloc(16384 * 2);
    unsigned short* W2lo  = (unsigned short*)alloc(16384 * 2);
    unsigned short* W3hi  = (unsigned short*)alloc(16384 * 2);
    unsigned short* W3lo  = (unsigned short*)alloc(16384 * 2);
    unsigned short* Wchi  = (unsigned short*)alloc(192 * 128 * 2);  // [Wp1;Wt1] concat
    unsigned short* Wclo  = (unsigned short*)alloc(192 * 128 * 2);
    float* bcat           = (float*)alloc(192 * 4);
    unsigned short* xb    = (unsigned short*)alloc((size_t)N * 128 * 2);
    unsigned short* hs    = (unsigned short*)alloc((size_t)N * 128 * 2);
    unsigned short* hb    = (unsigned short*)alloc((size_t)N * 128 * 2);
    unsigned short* hh    = (unsigned short*)alloc((size_t)N * 192 * 2);

    // degree + norm
    hipMemsetAsync(deg, 0, (size_t)N * 4, stream);
    deg_kernel<<<(E + 255) / 256, 256, 0, stream>>>(ei, deg, E);
    dinv_kernel<<<(N + 255) / 256, 256, 0, stream>>>(deg, dinv, N);

    // CSR build
    const int nb1 = (N + 1023) / 1024;
    scan1_kernel<<<nb1, 256, 0, stream>>>(deg, excl, chunk_sum, N);
    scan2_kernel<<<1, 128, 0, stream>>>(chunk_sum, chunk_off, nb1);
    scan3_kernel<<<(N + 255) / 256, 256, 0, stream>>>(excl, chunk_off, row_ptr, fill_pos, N, E);
    fill_kernel<<<(E + 255) / 256, 256, 0, stream>>>(ei, fill_pos, csr_src, E);

    // weight prep
    wsplit_kernel<<<64, 256, 0, stream>>>(W1, W1hi, W1lo, 128, 128);
    wsplit_kernel<<<64, 256, 0, stream>>>(W2, W2hi, W2lo, 128, 128);
    wsplit_kernel<<<64, 256, 0, stream>>>(W3, W3hi, W3lo, 128, 128);
    wsplit_kernel<<<64, 256, 0, stream>>>(Wp1, Wchi, Wclo, 128, 128);
    wsplit_kernel<<<32, 256, 0, stream>>>(Wt1, Wchi + 128 * 128, Wclo + 128 * 128, 128, 64);
    bcat_kernel<<<1, 256, 0, stream>>>(bp1, bt1, bcat);

    // x -> bf16
    round_kernel<<<(N * 32 + 255) / 256, 256, 0, stream>>>(x, xb, N * 32);

    const int gemm_blocks = (N + 63) / 64;
    const int pull_blocks = (N + 7) / 8;

    // layer 1: GEMM(xb) -> hs (scaled by dinv), pull(hs) -> hb
    gemm_kernel<8, false><<<gemm_blocks, 256, 0, stream>>>(xb, W1hi, W1lo, nullptr, dinv, hs, N);
    pull_kernel<<<pull_blocks, 256, 0, stream>>>(hs, row_ptr, csr_src, dinv, b1, hb, N);
    // layer 2
    gemm_kernel<8, false><<<gemm_blocks, 256, 0, stream>>>(hb, W2hi, W2lo, nullptr, dinv, hs, N);
    pull_kernel<<<pull_blocks, 256, 0, stream>>>(hs, row_ptr, csr_src, dinv, b2, hb, N);
    // layer 3
    gemm_kernel<8, false><<<gemm_blocks, 256, 0, stream>>>(hb, W3hi, W3lo, nullptr, dinv, hs, N);
    pull_kernel<<<pull_blocks, 256, 0, stream>>>(hs, row_ptr, csr_src, dinv, b3, hb, N);

    // fused heads: [N,192] = relu(hb @ [Wp1;Wt1] + bcat)
    gemm_kernel<12, true><<<gemm_blocks, 256, 0, stream>>>(hb, Wchi, Wclo, bcat, nullptr, hh, N);
    head_kernel<<<(N + 3) / 4, 256, 0, stream>>>(hh, Wp2, bp2, Wt2, bt2, out, N);
}

// Round 4
// 746.512 us; speedup vs baseline: 1.3736x; 1.1526x over previous
//
#include <hip/hip_runtime.h>

// ---------- types / helpers ----------
typedef __bf16 bf16x8 __attribute__((ext_vector_type(8)));
typedef unsigned short u16x8 __attribute__((ext_vector_type(8)));
typedef float f32x4 __attribute__((ext_vector_type(4)));

union BU {
    u16x8 u;
    bf16x8 b;
};

static __device__ __forceinline__ float b2f(unsigned short u) {
    return __uint_as_float(((unsigned)u) << 16);
}
static __device__ __forceinline__ unsigned short f2b(float f) {
    unsigned u = __float_as_uint(f);
    unsigned r = (u + 0x7FFF + ((u >> 16) & 1)) >> 16;  // RNE
    return (unsigned short)r;
}

// ---------- fused prep: round(x->bf16) + deg atomics + 5x wsplit + bcat ----------
__global__ __launch_bounds__(256) void prep_kernel(
    const float* __restrict__ x, unsigned short* __restrict__ xb, int n4,
    const int* __restrict__ ei, int* __restrict__ deg, int E,
    const float* __restrict__ W1, const float* __restrict__ W2, const float* __restrict__ W3,
    const float* __restrict__ Wp1, const float* __restrict__ Wt1,
    unsigned short* __restrict__ W1hi, unsigned short* __restrict__ W1lo,
    unsigned short* __restrict__ W2hi, unsigned short* __restrict__ W2lo,
    unsigned short* __restrict__ W3hi, unsigned short* __restrict__ W3lo,
    unsigned short* __restrict__ Wchi, unsigned short* __restrict__ Wclo,
    const float* __restrict__ bp1, const float* __restrict__ bt1, float* __restrict__ bcat,
    int rb, int db) {
    int b = blockIdx.x;
    int tid = threadIdx.x;
    if (b < rb) {  // round x -> bf16
        int i = b * 256 + tid;
        if (i < n4) {
            float4 v = *reinterpret_cast<const float4*>(x + (size_t)i * 4);
            ushort4 o;
            o.x = f2b(v.x); o.y = f2b(v.y); o.z = f2b(v.z); o.w = f2b(v.w);
            *reinterpret_cast<ushort4*>(xb + (size_t)i * 4) = o;
        }
        return;
    }
    b -= rb;
    if (b < db) {  // degree
        int e = b * 256 + tid;
        if (e < E) atomicAdd(&deg[ei[E + e]], 1);
        return;
    }
    b -= db;
    if (b < 288) {  // weight split+transpose
        const float* W;
        unsigned short *Whi, *Wlo;
        int lb, ncshift, total;
        if (b < 64)       { W = W1;  Whi = W1hi; Wlo = W1lo; lb = b;       ncshift = 7; total = 16384; }
        else if (b < 128) { W = W2;  Whi = W2hi; Wlo = W2lo; lb = b - 64;  ncshift = 7; total = 16384; }
        else if (b < 192) { W = W3;  Whi = W3hi; Wlo = W3lo; lb = b - 128; ncshift = 7; total = 16384; }
        else if (b < 256) { W = Wp1; Whi = Wchi; Wlo = Wclo; lb = b - 192; ncshift = 7; total = 16384; }
        else              { W = Wt1; Whi = Wchi + 128 * 128; Wlo = Wclo + 128 * 128; lb = b - 256; ncshift = 6; total = 8192; }
        int idx = lb * 256 + tid;
        if (idx < total) {
            int k = idx >> ncshift;
            int n = idx - (k << ncshift);
            float a = W[idx];
            unsigned short hb = f2b(a);
            Whi[(n << 7) + k] = hb;
            Wlo[(n << 7) + k] = f2b(a - b2f(hb));
        }
        return;
    }
    // bcat
    if (tid < 128) bcat[tid] = bp1[tid];
    else if (tid < 192) bcat[tid] = bt1[tid - 128];
}

// ---------- hierarchical exclusive scan (1024 elems / block) ----------
__global__ __launch_bounds__(256) void scan1_kernel(const int* __restrict__ deg,
                                                    int* __restrict__ excl,
                                                    int* __restrict__ chunk_sum, int n) {
    __shared__ int s[256];
    int tid = threadIdx.x;
    int base = blockIdx.x * 1024 + tid * 4;
    int v[4], sum = 0;
#pragma unroll
    for (int j = 0; j < 4; ++j) {
        v[j] = (base + j < n) ? deg[base + j] : 0;
        sum += v[j];
    }
    s[tid] = sum;
    __syncthreads();
    for (int off = 1; off < 256; off <<= 1) {
        int t = (tid >= off) ? s[tid - off] : 0;
        __syncthreads();
        s[tid] += t;
        __syncthreads();
    }
    int run = s[tid] - sum;
#pragma unroll
    for (int j = 0; j < 4; ++j) {
        if (base + j < n) excl[base + j] = run;
        run += v[j];
    }
    if (tid == 255) chunk_sum[blockIdx.x] = s[255];
}

__global__ __launch_bounds__(128) void scan2_kernel(const int* __restrict__ chunk_sum,
                                                    int* __restrict__ chunk_off, int nc) {
    __shared__ int s[128];
    int tid = threadIdx.x;
    int v = (tid < nc) ? chunk_sum[tid] : 0;
    s[tid] = v;
    __syncthreads();
    for (int off = 1; off < 128; off <<= 1) {
        int t = (tid >= off) ? s[tid - off] : 0;
        __syncthreads();
        s[tid] += t;
        __syncthreads();
    }
    if (tid < nc) chunk_off[tid] = s[tid] - v;
}

// row_ptr/fill_pos + dinv fused
__global__ __launch_bounds__(256) void scan3_kernel(const int* __restrict__ excl,
                                                    const int* __restrict__ chunk_off,
                                                    const int* __restrict__ deg,
                                                    int* __restrict__ row_ptr,
                                                    int* __restrict__ fill_pos,
                                                    float* __restrict__ dinv, int n, int E) {
    int i = blockIdx.x * 256 + threadIdx.x;
    if (i < n) {
        int r = excl[i] + chunk_off[i >> 10];
        row_ptr[i] = r;
        fill_pos[i] = r;
        dinv[i] = rsqrtf((float)deg[i] + 1.0f);
    }
    if (i == 0) row_ptr[n] = E;
}

// ---------- shared GEMM accumulate body ----------
template <int NT>
static __device__ __forceinline__ void gemm_acc(const unsigned short* __restrict__ A,
                                                const unsigned short* __restrict__ Whi,
                                                const unsigned short* __restrict__ Wlo,
                                                int arow, int m16, int quad, f32x4* acc) {
    const unsigned short* Arow = A + (size_t)arow * 128 + quad * 8;
#pragma unroll
    for (int kb = 0; kb < 4; ++kb) {
        BU a;
        a.u = *reinterpret_cast<const u16x8*>(Arow + kb * 32);
#pragma unroll
        for (int t = 0; t < NT; ++t) {
            size_t woff = (size_t)(t * 16 + m16) * 128 + quad * 8 + kb * 32;
            BU bh, bl;
            bh.u = *reinterpret_cast<const u16x8*>(Whi + woff);
            bl.u = *reinterpret_cast<const u16x8*>(Wlo + woff);
            acc[t] = __builtin_amdgcn_mfma_f32_16x16x32_bf16(a.b, bh.b, acc[t], 0, 0, 0);
            acc[t] = __builtin_amdgcn_mfma_f32_16x16x32_bf16(a.b, bl.b, acc[t], 0, 0, 0);
        }
    }
}

// hs-store epilogue: C = (A@W) * dinv[row] -> bf16
template <int NT>
static __device__ __forceinline__ void gemm_store_scaled(const float* __restrict__ dinv,
                                                         unsigned short* __restrict__ C,
                                                         int row_base, int m16, int quad,
                                                         f32x4* acc, int nrows) {
#pragma unroll
    for (int t = 0; t < NT; ++t) {
#pragma unroll
        for (int r = 0; r < 4; ++r) {
            int row = row_base + quad * 4 + r;
            if (row < nrows)
                C[(size_t)row * (NT * 16) + t * 16 + m16] = f2b(acc[t][r] * dinv[row]);
        }
    }
}

// plain GEMM kernel (layers 2,3)
template <int NT>
__global__ __launch_bounds__(256) void gemm_kernel(const unsigned short* __restrict__ A,
                                                   const unsigned short* __restrict__ Whi,
                                                   const unsigned short* __restrict__ Wlo,
                                                   const float* __restrict__ dinv,
                                                   unsigned short* __restrict__ C, int nrows) {
    const int tid = threadIdx.x;
    const int wave = tid >> 6, lane = tid & 63;
    const int m16 = lane & 15, quad = lane >> 4;
    const int row_base = blockIdx.x * 64 + wave * 16;
    int arow = row_base + m16;
    if (arow >= nrows) arow = nrows - 1;
    f32x4 acc[NT] = {};
    gemm_acc<NT>(A, Whi, Wlo, arow, m16, quad, acc);
    gemm_store_scaled<NT>(dinv, C, row_base, m16, quad, acc, nrows);
}

// ---------- fused: layer-1 GEMM || CSR fill ----------
__global__ __launch_bounds__(256) void fg_kernel(const unsigned short* __restrict__ A,
                                                 const unsigned short* __restrict__ Whi,
                                                 const unsigned short* __restrict__ Wlo,
                                                 const float* __restrict__ dinv,
                                                 unsigned short* __restrict__ C, int nrows,
                                                 int gemm_blocks,
                                                 const int* __restrict__ ei,
                                                 int* __restrict__ fill_pos,
                                                 int* __restrict__ csr_src, int E) {
    const int tid = threadIdx.x;
    if ((int)blockIdx.x < gemm_blocks) {
        const int wave = tid >> 6, lane = tid & 63;
        const int m16 = lane & 15, quad = lane >> 4;
        const int row_base = blockIdx.x * 64 + wave * 16;
        int arow = row_base + m16;
        if (arow >= nrows) arow = nrows - 1;
        f32x4 acc[8] = {};
        gemm_acc<8>(A, Whi, Wlo, arow, m16, quad, acc);
        gemm_store_scaled<8>(dinv, C, row_base, m16, quad, acc, nrows);
    } else {
        int e = (blockIdx.x - gemm_blocks) * 256 + tid;
        if (e < E) {
            int dst = ei[E + e];
            int p = atomicAdd(&fill_pos[dst], 1);
            __builtin_nontemporal_store(ei[e], &csr_src[p]);
        }
    }
}

// ---------- pull aggregation: 16 lanes/node, 8 feats/lane, unroll-4 ----------
__global__ __launch_bounds__(256) void pull_kernel(const unsigned short* __restrict__ hs,
                                                   const int* __restrict__ row_ptr,
                                                   const int* __restrict__ csr_src,
                                                   const float* __restrict__ dinv,
                                                   const float* __restrict__ bias,
                                                   unsigned short* __restrict__ out, int n) {
    int t = blockIdx.x * 256 + threadIdx.x;
    int node = t >> 4;
    if (node >= n) return;
    int f = (t & 15) * 8;
    BU sv;
    sv.u = *reinterpret_cast<const u16x8*>(hs + (size_t)node * 128 + f);
    float a[8];
#pragma unroll
    for (int j = 0; j < 8; ++j) a[j] = b2f(sv.u[j]);  // self loop
    int s0 = row_ptr[node], s1 = row_ptr[node + 1];
    int e = s0;
    for (; e + 4 <= s1; e += 4) {
        int src0 = csr_src[e], src1 = csr_src[e + 1], src2 = csr_src[e + 2], src3 = csr_src[e + 3];
        BU h0, h1, h2, h3;
        h0.u = *reinterpret_cast<const u16x8*>(hs + (size_t)src0 * 128 + f);
        h1.u = *reinterpret_cast<const u16x8*>(hs + (size_t)src1 * 128 + f);
        h2.u = *reinterpret_cast<const u16x8*>(hs + (size_t)src2 * 128 + f);
        h3.u = *reinterpret_cast<const u16x8*>(hs + (size_t)src3 * 128 + f);
#pragma unroll
        for (int j = 0; j < 8; ++j)
            a[j] += (b2f(h0.u[j]) + b2f(h1.u[j])) + (b2f(h2.u[j]) + b2f(h3.u[j]));
    }
    for (; e < s1; ++e) {
        int src0 = csr_src[e];
        BU h0;
        h0.u = *reinterpret_cast<const u16x8*>(hs + (size_t)src0 * 128 + f);
#pragma unroll
        for (int j = 0; j < 8; ++j) a[j] += b2f(h0.u[j]);
    }
    float d = dinv[node];
    BU o;
#pragma unroll
    for (int j = 0; j < 8; ++j) o.u[j] = f2b(fmaxf(a[j] * d + bias[f + j], 0.f));
    *reinterpret_cast<u16x8*>(out + (size_t)node * 128 + f) = o.u;
}

// ---------- fused heads GEMM + in-register reduction -> out[N,3] f32 ----------
__global__ __launch_bounds__(256) void gemmh_kernel(const unsigned short* __restrict__ A,
                                                    const unsigned short* __restrict__ Whi,
                                                    const unsigned short* __restrict__ Wlo,
                                                    const float* __restrict__ bcat,
                                                    const float* __restrict__ Wp2,
                                                    const float* __restrict__ bp2,
                                                    const float* __restrict__ Wt2,
                                                    const float* __restrict__ bt2,
                                                    float* __restrict__ out, int nrows) {
    const int tid = threadIdx.x;
    const int wave = tid >> 6, lane = tid & 63;
    const int m16 = lane & 15, quad = lane >> 4;
    const int row_base = blockIdx.x * 64 + wave * 16;
    int arow = row_base + m16;
    if (arow >= nrows) arow = nrows - 1;
    f32x4 acc[12] = {};
    gemm_acc<12>(A, Whi, Wlo, arow, m16, quad, acc);
#pragma unroll
    for (int r = 0; r < 4; ++r) {
        int row = row_base + quad * 4 + r;
        float p0 = 0.f, p1 = 0.f, tt = 0.f;
#pragma unroll
        for (int t = 0; t < 12; ++t) {
            int c = t * 16 + m16;
            float v = fmaxf(acc[t][r] + bcat[c], 0.f);
            if (t < 8) {
                p0 += v * Wp2[c * 2 + 0];
                p1 += v * Wp2[c * 2 + 1];
            } else {
                tt += v * Wt2[c - 128];
            }
        }
#pragma unroll
        for (int mask = 1; mask < 16; mask <<= 1) {
            p0 += __shfl_xor(p0, mask);
            p1 += __shfl_xor(p1, mask);
            tt += __shfl_xor(tt, mask);
        }
        if (m16 == 0 && row < nrows) {
            out[(size_t)row * 3 + 0] = p0 + bp2[0];
            out[(size_t)row * 3 + 1] = p1 + bp2[1];
            out[(size_t)row * 3 + 2] = tt + bt2[0];
        }
    }
}

// ---------- launcher ----------
extern "C" void kernel_launch(void* const* d_in, const int* in_sizes, int n_in,
                              void* d_out, int out_size, void* d_ws, size_t ws_size,
                              hipStream_t stream) {
    const int N = in_sizes[0] / 128;
    const int E = in_sizes[1] / 2;

    const float* x   = (const float*)d_in[0];
    const int* ei    = (const int*)d_in[1];
    const float* W1  = (const float*)d_in[2];
    const float* b1  = (const float*)d_in[3];
    const float* W2  = (const float*)d_in[4];
    const float* b2  = (const float*)d_in[5];
    const float* W3  = (const float*)d_in[6];
    const float* b3  = (const float*)d_in[7];
    const float* Wp1 = (const float*)d_in[8];
    const float* bp1 = (const float*)d_in[9];
    const float* Wp2 = (const float*)d_in[10];
    const float* bp2 = (const float*)d_in[11];
    const float* Wt1 = (const float*)d_in[12];
    const float* bt1 = (const float*)d_in[13];
    const float* Wt2 = (const float*)d_in[14];
    const float* bt2 = (const float*)d_in[15];
    float* out = (float*)d_out;

    char* ws = (char*)d_ws;
    size_t off = 0;
    auto alloc = [&](size_t bytes) {
        void* p = ws + off;
        off += (bytes + 255) & ~(size_t)255;
        return p;
    };
    int* deg        = (int*)alloc((size_t)N * 4);
    float* dinv     = (float*)alloc((size_t)N * 4);
    int* excl       = (int*)alloc((size_t)N * 4);
    int* row_ptr    = (int*)alloc((size_t)(N + 1) * 4);
    int* fill_pos   = (int*)alloc((size_t)N * 4);
    int* chunk_sum  = (int*)alloc(128 * 4);
    int* chunk_off  = (int*)alloc(128 * 4);
    int* csr_src    = (int*)alloc((size_t)E * 4);
    unsigned short* W1hi = (unsigned short*)alloc(16384 * 2);
    unsigned short* W1lo = (unsigned short*)alloc(16384 * 2);
    unsigned short* W2hi = (unsigned short*)alloc(16384 * 2);
    unsigned short* W2lo = (unsigned short*)alloc(16384 * 2);
    unsigned short* W3hi = (unsigned short*)alloc(16384 * 2);
    unsigned short* W3lo = (unsigned short*)alloc(16384 * 2);
    unsigned short* Wchi = (unsigned short*)alloc(192 * 128 * 2);
    unsigned short* Wclo = (unsigned short*)alloc(192 * 128 * 2);
    float* bcat          = (float*)alloc(192 * 4);
    unsigned short* xb   = (unsigned short*)alloc((size_t)N * 128 * 2);
    unsigned short* hs   = (unsigned short*)alloc((size_t)N * 128 * 2);
    unsigned short* hb   = (unsigned short*)alloc((size_t)N * 128 * 2);

    hipMemsetAsync(deg, 0, (size_t)N * 4, stream);

    // fused prep
    const int n4 = N * 32;
    const int rb = (n4 + 255) / 256;
    const int db = (E + 255) / 256;
    prep_kernel<<<rb + db + 288 + 1, 256, 0, stream>>>(
        x, xb, n4, ei, deg, E, W1, W2, W3, Wp1, Wt1,
        W1hi, W1lo, W2hi, W2lo, W3hi, W3lo, Wchi, Wclo, bp1, bt1, bcat, rb, db);

    // CSR scan
    const int nb1 = (N + 1023) / 1024;
    scan1_kernel<<<nb1, 256, 0, stream>>>(deg, excl, chunk_sum, N);
    scan2_kernel<<<1, 128, 0, stream>>>(chunk_sum, chunk_off, nb1);
    scan3_kernel<<<(N + 255) / 256, 256, 0, stream>>>(excl, chunk_off, deg, row_ptr, fill_pos, dinv, N, E);

    const int gb = (N + 63) / 64;
    const int fb = (E + 255) / 256;
    const int pull_blocks = (N * 16 + 255) / 256;

    // layer 1 GEMM || CSR fill
    fg_kernel<<<gb + fb, 256, 0, stream>>>(xb, W1hi, W1lo, dinv, hs, N, gb, ei, fill_pos, csr_src, E);
    pull_kernel<<<pull_blocks, 256, 0, stream>>>(hs, row_ptr, csr_src, dinv, b1, hb, N);
    // layer 2
    gemm_kernel<8><<<gb, 256, 0, stream>>>(hb, W2hi, W2lo, dinv, hs, N);
    pull_kernel<<<pull_blocks, 256, 0, stream>>>(hs, row_ptr, csr_src, dinv, b2, hb, N);
    // layer 3
    gemm_kernel<8><<<gb, 256, 0, stream>>>(hb, W3hi, W3lo, dinv, hs, N);
    pull_kernel<<<pull_blocks, 256, 0, stream>>>(hs, row_ptr, csr_src, dinv, b3, hb, N);

    // fused heads
    gemmh_kernel<<<gb, 256, 0, stream>>>(hb, Wchi, Wclo, bcat, Wp2, bp2, Wt2, bt2, out, N);
}